// Round 1
// baseline (3336.906 us; speedup 1.0000x reference)
//
#include <hip/hip_runtime.h>

#define TSEQ  2048
#define CDIM  2048
#define NHEADS 32
#define NKV    8
#define HSZ    64
#define BATCH  2
#define MROWS  (BATCH * TSEQ)            // 4096
#define NQKV   (CDIM + 2 * NKV * HSZ)    // 3072

// ---------------------------------------------------------------------------
// GEMM: C[M,N] = A[M,K] @ B[K,N] + bias[N]   (fp32, 128x128x8 tiles)
// ---------------------------------------------------------------------------
__global__ __launch_bounds__(256)
void gemm_bias_f32(const float* __restrict__ A, const float* __restrict__ B,
                   const float* __restrict__ bias, float* __restrict__ C,
                   int M, int N, int K) {
    constexpr int BM = 128, BN = 128, BK = 8;
    __shared__ float As[BK][BM];
    __shared__ float Bs[BK][BN];

    const int t  = threadIdx.x;
    const int tx = t & 15;          // 0..15 -> col group
    const int ty = t >> 4;          // 0..15 -> row group
    const int br = blockIdx.y;
    const int bc = blockIdx.x;

    // global load assignments
    const int a_row = t >> 1;            // 0..127
    const int a_col = (t & 1) << 2;      // 0 or 4
    const int b_row = t >> 5;            // 0..7
    const int b_col = (t & 31) << 2;     // 0..124

    const float* Aptr = A + (size_t)(br * BM + a_row) * K + a_col;
    const float* Bptr = B + (size_t)b_row * N + (size_t)bc * BN + b_col;

    float acc[8][8];
#pragma unroll
    for (int i = 0; i < 8; ++i)
#pragma unroll
        for (int j = 0; j < 8; ++j) acc[i][j] = 0.0f;

    // prefetch first k-slice into registers
    float4 av = *(const float4*)Aptr;
    float4 bv = *(const float4*)Bptr;

    for (int k0 = 0; k0 < K; k0 += BK) {
        __syncthreads();   // previous iteration's LDS reads complete
        As[a_col + 0][a_row] = av.x;
        As[a_col + 1][a_row] = av.y;
        As[a_col + 2][a_row] = av.z;
        As[a_col + 3][a_row] = av.w;
        *(float4*)&Bs[b_row][b_col] = bv;
        __syncthreads();   // writes visible

        if (k0 + BK < K) { // prefetch next slice (overlaps with compute below)
            av = *(const float4*)(Aptr + k0 + BK);
            bv = *(const float4*)(Bptr + (size_t)(k0 + BK) * N);
        }

#pragma unroll
        for (int kk = 0; kk < BK; ++kk) {
            float4 a0 = *(const float4*)&As[kk][ty * 8];
            float4 a1 = *(const float4*)&As[kk][ty * 8 + 4];
            float4 b0 = *(const float4*)&Bs[kk][tx * 8];
            float4 b1 = *(const float4*)&Bs[kk][tx * 8 + 4];
            float ar[8] = {a0.x, a0.y, a0.z, a0.w, a1.x, a1.y, a1.z, a1.w};
            float brr[8] = {b0.x, b0.y, b0.z, b0.w, b1.x, b1.y, b1.z, b1.w};
#pragma unroll
            for (int i = 0; i < 8; ++i)
#pragma unroll
                for (int j = 0; j < 8; ++j)
                    acc[i][j] = fmaf(ar[i], brr[j], acc[i][j]);
        }
    }

#pragma unroll
    for (int i = 0; i < 8; ++i) {
        const int row = br * BM + ty * 8 + i;
#pragma unroll
        for (int j = 0; j < 8; j += 4) {
            const int col = bc * BN + tx * 8 + j;
            float4 bb = *(const float4*)&bias[col];
            float4 c;
            c.x = acc[i][j + 0] + bb.x;
            c.y = acc[i][j + 1] + bb.y;
            c.z = acc[i][j + 2] + bb.z;
            c.w = acc[i][j + 3] + bb.w;
            *(float4*)&C[(size_t)row * N + col] = c;
        }
    }
}

// ---------------------------------------------------------------------------
// RoPE (in-place on qkv buffer): q heads 0..31 at col h*64, k heads at
// col 2048 + (h-32)*64.  Pairs are (2i, 2i+1), freq index i, pos t = row % T.
// ---------------------------------------------------------------------------
__global__ void rope_f32(float* __restrict__ qkv,
                         const float* __restrict__ cs,
                         const float* __restrict__ sn) {
    const int total = MROWS * (NHEADS + NKV) * (HSZ / 2);  // 4096*40*32
    int idx = blockIdx.x * blockDim.x + threadIdx.x;
    if (idx >= total) return;
    const int i    = idx & 31;
    int tmp        = idx >> 5;
    const int head = tmp % (NHEADS + NKV);
    const int row  = tmp / (NHEADS + NKV);
    const int tpos = row & (TSEQ - 1);
    const int col  = (head < NHEADS) ? head * HSZ + 2 * i
                                     : CDIM + (head - NHEADS) * HSZ + 2 * i;
    float* p = qkv + (size_t)row * NQKV + col;
    float2 v = *(float2*)p;
    const float c = cs[tpos * (HSZ / 2) + i];
    const float s = sn[tpos * (HSZ / 2) + i];
    float2 o;
    o.x = v.x * c - v.y * s;
    o.y = v.x * s + v.y * c;
    *(float2*)p = o;
}

// ---------------------------------------------------------------------------
// Flash-style causal GQA attention, fp32.
// grid = (T/64, NH, B), block = 256.  Each block: one 64-row q-tile for one
// head.  Per thread: 4x4 S microtile (rows qr*4+a, cols kc*4+c) and a 4x4
// O microtile (rows qr*4+a, dcols kc*4+c).
// ---------------------------------------------------------------------------
__global__ __launch_bounds__(256)
void attn_f32(const float* __restrict__ qkv, float* __restrict__ y) {
    __shared__ float Qs[64][68];
    __shared__ float Ks[64][68];
    __shared__ float Vs[64][68];
    __shared__ float Ps[64][68];

    const int t  = threadIdx.x;
    const int qt = blockIdx.x;
    const int h  = blockIdx.y;
    const int b  = blockIdx.z;
    const int g  = h >> 2;          // kv group (rep = 4)
    const int qr = t >> 4;          // 0..15
    const int kc = t & 15;          // 0..15

    const int lr = t >> 2;          // load row 0..63
    const int lc = (t & 3) << 4;    // load col base {0,16,32,48}

    // ---- load Q tile (pre-scaled by 1/sqrt(HS)) ----
    {
        const float* src =
            qkv + (size_t)(b * TSEQ + qt * 64 + lr) * NQKV + h * HSZ + lc;
#pragma unroll
        for (int i = 0; i < 4; ++i) {
            float4 v = *(const float4*)(src + i * 4);
            v.x *= 0.125f; v.y *= 0.125f; v.z *= 0.125f; v.w *= 0.125f;
            *(float4*)&Qs[lr][lc + i * 4] = v;
        }
    }

    float o[4][4];
#pragma unroll
    for (int a = 0; a < 4; ++a)
#pragma unroll
        for (int c = 0; c < 4; ++c) o[a][c] = 0.0f;
    float m_run[4] = {-1e30f, -1e30f, -1e30f, -1e30f};
    float l_run[4] = {0.0f, 0.0f, 0.0f, 0.0f};

    // ---- prefetch K/V tile 0 into registers ----
    float4 kr[4], vr[4];
    {
        const float* src = qkv + (size_t)(b * TSEQ + lr) * NQKV;
#pragma unroll
        for (int i = 0; i < 4; ++i) {
            kr[i] = *(const float4*)(src + CDIM + g * HSZ + lc + i * 4);
            vr[i] = *(const float4*)(src + CDIM + NKV * HSZ + g * HSZ + lc + i * 4);
        }
    }

    for (int kt = 0; kt <= qt; ++kt) {
        __syncthreads();   // previous tile's LDS reads complete (also Q visibility)
#pragma unroll
        for (int i = 0; i < 4; ++i) {
            *(float4*)&Ks[lr][lc + i * 4] = kr[i];
            *(float4*)&Vs[lr][lc + i * 4] = vr[i];
        }
        __syncthreads();

        if (kt < qt) {  // prefetch next K/V tile
            const float* src = qkv + (size_t)(b * TSEQ + (kt + 1) * 64 + lr) * NQKV;
#pragma unroll
            for (int i = 0; i < 4; ++i) {
                kr[i] = *(const float4*)(src + CDIM + g * HSZ + lc + i * 4);
                vr[i] = *(const float4*)(src + CDIM + NKV * HSZ + g * HSZ + lc + i * 4);
            }
        }

        // ---- scores: S = (Q/8) @ K^T ----
        float s[4][4];
#pragma unroll
        for (int a = 0; a < 4; ++a)
#pragma unroll
            for (int c = 0; c < 4; ++c) s[a][c] = 0.0f;

#pragma unroll
        for (int d0 = 0; d0 < 64; d0 += 4) {
            float4 qv[4], kv[4];
#pragma unroll
            for (int a = 0; a < 4; ++a)
                qv[a] = *(const float4*)&Qs[qr * 4 + a][d0];
#pragma unroll
            for (int c = 0; c < 4; ++c)
                kv[c] = *(const float4*)&Ks[kc * 4 + c][d0];
#pragma unroll
            for (int a = 0; a < 4; ++a)
#pragma unroll
                for (int c = 0; c < 4; ++c)
                    s[a][c] += qv[a].x * kv[c].x + qv[a].y * kv[c].y +
                               qv[a].z * kv[c].z + qv[a].w * kv[c].w;
        }

        if (kt == qt) {  // causal mask on diagonal tile (local indices suffice)
#pragma unroll
            for (int a = 0; a < 4; ++a)
#pragma unroll
                for (int c = 0; c < 4; ++c)
                    if (kc * 4 + c > qr * 4 + a) s[a][c] = -1e30f;
        }

        // ---- online softmax (rows shared by 16 lanes with equal qr) ----
#pragma unroll
        for (int a = 0; a < 4; ++a) {
            float mx = fmaxf(fmaxf(s[a][0], s[a][1]), fmaxf(s[a][2], s[a][3]));
            mx = fmaxf(mx, __shfl_xor(mx, 1));
            mx = fmaxf(mx, __shfl_xor(mx, 2));
            mx = fmaxf(mx, __shfl_xor(mx, 4));
            mx = fmaxf(mx, __shfl_xor(mx, 8));
            const float mnew  = fmaxf(m_run[a], mx);
            const float alpha = __expf(m_run[a] - mnew);
            const float p0 = __expf(s[a][0] - mnew);
            const float p1 = __expf(s[a][1] - mnew);
            const float p2 = __expf(s[a][2] - mnew);
            const float p3 = __expf(s[a][3] - mnew);
            float sum = p0 + p1 + p2 + p3;
            sum += __shfl_xor(sum, 1);
            sum += __shfl_xor(sum, 2);
            sum += __shfl_xor(sum, 4);
            sum += __shfl_xor(sum, 8);
            l_run[a] = l_run[a] * alpha + sum;
            m_run[a] = mnew;
            o[a][0] *= alpha; o[a][1] *= alpha; o[a][2] *= alpha; o[a][3] *= alpha;
            // P rows qr*4+a are wave-private (written and read by the same
            // 16-lane groups of this wave) -> no extra barrier needed.
            Ps[qr * 4 + a][kc * 4 + 0] = p0;
            Ps[qr * 4 + a][kc * 4 + 1] = p1;
            Ps[qr * 4 + a][kc * 4 + 2] = p2;
            Ps[qr * 4 + a][kc * 4 + 3] = p3;
        }

        // ---- O += P @ V ----
#pragma unroll
        for (int k0 = 0; k0 < 64; k0 += 4) {
            float4 vv0 = *(const float4*)&Vs[k0 + 0][kc * 4];
            float4 vv1 = *(const float4*)&Vs[k0 + 1][kc * 4];
            float4 vv2 = *(const float4*)&Vs[k0 + 2][kc * 4];
            float4 vv3 = *(const float4*)&Vs[k0 + 3][kc * 4];
#pragma unroll
            for (int a = 0; a < 4; ++a) {
                float4 pa = *(const float4*)&Ps[qr * 4 + a][k0];
                o[a][0] += pa.x * vv0.x + pa.y * vv1.x + pa.z * vv2.x + pa.w * vv3.x;
                o[a][1] += pa.x * vv0.y + pa.y * vv1.y + pa.z * vv2.y + pa.w * vv3.y;
                o[a][2] += pa.x * vv0.z + pa.y * vv1.z + pa.z * vv2.z + pa.w * vv3.z;
                o[a][3] += pa.x * vv0.w + pa.y * vv1.w + pa.z * vv2.w + pa.w * vv3.w;
            }
        }
    }

    // ---- finalize and store y[b,t,h*64+d] ----
#pragma unroll
    for (int a = 0; a < 4; ++a) {
        const float inv = 1.0f / l_run[a];
        float4 ov;
        ov.x = o[a][0] * inv;
        ov.y = o[a][1] * inv;
        ov.z = o[a][2] * inv;
        ov.w = o[a][3] * inv;
        *(float4*)&y[(size_t)(b * TSEQ + qt * 64 + qr * 4 + a) * CDIM +
                     h * HSZ + kc * 4] = ov;
    }
}

// ---------------------------------------------------------------------------
extern "C" void kernel_launch(void* const* d_in, const int* in_sizes, int n_in,
                              void* d_out, int out_size, void* d_ws, size_t ws_size,
                              hipStream_t stream) {
    const float* x     = (const float*)d_in[0];
    const float* fcos  = (const float*)d_in[1];
    const float* fsin  = (const float*)d_in[2];
    const float* Wqkv  = (const float*)d_in[3];
    const float* bqkv  = (const float*)d_in[4];
    const float* Wproj = (const float*)d_in[5];
    const float* bproj = (const float*)d_in[6];
    float* out = (float*)d_out;

    float* qkv = (float*)d_ws;                         // 4096 x 3072 f32 (50.3 MB)
    float* y   = qkv + (size_t)MROWS * NQKV;           // 4096 x 2048 f32 (33.6 MB)

    // 1) QKV projection: (4096 x 2048) @ (2048 x 3072) + bias
    gemm_bias_f32<<<dim3(NQKV / 128, MROWS / 128), 256, 0, stream>>>(
        x, Wqkv, bqkv, qkv, MROWS, NQKV, CDIM);

    // 2) RoPE in-place on q and k slices
    {
        const int total = MROWS * (NHEADS + NKV) * (HSZ / 2);
        rope_f32<<<(total + 255) / 256, 256, 0, stream>>>(qkv, fcos, fsin);
    }

    // 3) causal GQA attention -> y (4096 x 2048)
    attn_f32<<<dim3(TSEQ / 64, NHEADS, BATCH), 256, 0, stream>>>(qkv, y);

    // 4) output projection: (4096 x 2048) @ (2048 x 2048) + bias
    gemm_bias_f32<<<dim3(CDIM / 128, MROWS / 128), 256, 0, stream>>>(
        y, Wproj, bproj, out, MROWS, CDIM, CDIM);
}

// Round 2
// 1316.986 us; speedup vs baseline: 2.5337x; 2.5337x over previous
//
#include <hip/hip_runtime.h>
#include <hip/hip_bf16.h>

#define TSEQ  2048
#define CDIM  2048
#define NHEADS 32
#define NKV    8
#define HSZ    64
#define BATCH  2
#define MROWS  (BATCH * TSEQ)            // 4096
#define NQKV   (CDIM + 2 * NKV * HSZ)    // 3072

typedef __attribute__((ext_vector_type(8))) short bf16x8;
typedef __attribute__((ext_vector_type(4))) float f32x4;

static __device__ __forceinline__ short f2bf(float f) {
    __hip_bfloat16 h = __float2bfloat16(f);
    short s;
    __builtin_memcpy(&s, &h, 2);
    return s;
}

// ---------------------------------------------------------------------------
// GEMM: C[M,N] = A[M,K] @ B[K,N] + bias[N]   (fp32, 128x128x8 tiles)
// ---------------------------------------------------------------------------
__global__ __launch_bounds__(256)
void gemm_bias_f32(const float* __restrict__ A, const float* __restrict__ B,
                   const float* __restrict__ bias, float* __restrict__ C,
                   int M, int N, int K) {
    constexpr int BM = 128, BN = 128, BK = 8;
    __shared__ float As[BK][BM];
    __shared__ float Bs[BK][BN];

    const int t  = threadIdx.x;
    const int tx = t & 15;
    const int ty = t >> 4;
    const int br = blockIdx.y;
    const int bc = blockIdx.x;

    const int a_row = t >> 1;
    const int a_col = (t & 1) << 2;
    const int b_row = t >> 5;
    const int b_col = (t & 31) << 2;

    const float* Aptr = A + (size_t)(br * BM + a_row) * K + a_col;
    const float* Bptr = B + (size_t)b_row * N + (size_t)bc * BN + b_col;

    float acc[8][8];
#pragma unroll
    for (int i = 0; i < 8; ++i)
#pragma unroll
        for (int j = 0; j < 8; ++j) acc[i][j] = 0.0f;

    float4 av = *(const float4*)Aptr;
    float4 bv = *(const float4*)Bptr;

    for (int k0 = 0; k0 < K; k0 += BK) {
        __syncthreads();
        As[a_col + 0][a_row] = av.x;
        As[a_col + 1][a_row] = av.y;
        As[a_col + 2][a_row] = av.z;
        As[a_col + 3][a_row] = av.w;
        *(float4*)&Bs[b_row][b_col] = bv;
        __syncthreads();

        if (k0 + BK < K) {
            av = *(const float4*)(Aptr + k0 + BK);
            bv = *(const float4*)(Bptr + (size_t)(k0 + BK) * N);
        }

#pragma unroll
        for (int kk = 0; kk < BK; ++kk) {
            float4 a0 = *(const float4*)&As[kk][ty * 8];
            float4 a1 = *(const float4*)&As[kk][ty * 8 + 4];
            float4 b0 = *(const float4*)&Bs[kk][tx * 8];
            float4 b1 = *(const float4*)&Bs[kk][tx * 8 + 4];
            float ar[8] = {a0.x, a0.y, a0.z, a0.w, a1.x, a1.y, a1.z, a1.w};
            float brr[8] = {b0.x, b0.y, b0.z, b0.w, b1.x, b1.y, b1.z, b1.w};
#pragma unroll
            for (int i = 0; i < 8; ++i)
#pragma unroll
                for (int j = 0; j < 8; ++j)
                    acc[i][j] = fmaf(ar[i], brr[j], acc[i][j]);
        }
    }

#pragma unroll
    for (int i = 0; i < 8; ++i) {
        const int row = br * BM + ty * 8 + i;
#pragma unroll
        for (int j = 0; j < 8; j += 4) {
            const int col = bc * BN + tx * 8 + j;
            float4 bb = *(const float4*)&bias[col];
            float4 c;
            c.x = acc[i][j + 0] + bb.x;
            c.y = acc[i][j + 1] + bb.y;
            c.z = acc[i][j + 2] + bb.z;
            c.w = acc[i][j + 3] + bb.w;
            *(float4*)&C[(size_t)row * N + col] = c;
        }
    }
}

// ---------------------------------------------------------------------------
// RoPE + cast to bf16, per-head layouts:
//   Qh[b][h][T][64]  (pre-scaled by 1/8 = 1/sqrt(HS))
//   Kh[b][g][T][64]
// ---------------------------------------------------------------------------
__global__ void repack_qk(const float* __restrict__ qkv,
                          const float* __restrict__ cs,
                          const float* __restrict__ sn,
                          short* __restrict__ Qh, short* __restrict__ Kh) {
    const int total = MROWS * (NHEADS + NKV) * (HSZ / 2);
    int idx = blockIdx.x * blockDim.x + threadIdx.x;
    if (idx >= total) return;
    const int i    = idx & 31;
    int tmp        = idx >> 5;
    const int head = tmp % (NHEADS + NKV);
    const int row  = tmp / (NHEADS + NKV);
    const int tpos = row & (TSEQ - 1);
    const int b    = row >> 11;                      // row / TSEQ
    const float c  = cs[tpos * (HSZ / 2) + i];
    const float s  = sn[tpos * (HSZ / 2) + i];
    const int col  = (head < NHEADS) ? head * HSZ + 2 * i
                                     : CDIM + (head - NHEADS) * HSZ + 2 * i;
    float2 v = *(const float2*)(qkv + (size_t)row * NQKV + col);
    const float re = v.x * c - v.y * s;
    const float im = v.x * s + v.y * c;
    if (head < NHEADS) {
        size_t o = (((size_t)(b * NHEADS + head)) * TSEQ + tpos) * HSZ + 2 * i;
        Qh[o]     = f2bf(re * 0.125f);
        Qh[o + 1] = f2bf(im * 0.125f);
    } else {
        const int kh = head - NHEADS;
        size_t o = (((size_t)(b * NKV + kh)) * TSEQ + tpos) * HSZ + 2 * i;
        Kh[o]     = f2bf(re);
        Kh[o + 1] = f2bf(im);
    }
}

// ---------------------------------------------------------------------------
// V -> bf16, transposed: Vt[b][g][d=64][T]
// ---------------------------------------------------------------------------
__global__ __launch_bounds__(256)
void transpose_v(const float* __restrict__ qkv, short* __restrict__ Vt) {
    __shared__ float tile[64][65];
    const int tt = blockIdx.x, g = blockIdx.y, b = blockIdx.z;
    const int t  = threadIdx.x;
    const int trow = t >> 2;
    const int cb   = (t & 3) * 16;
    const float* src = qkv + (size_t)(b * TSEQ + tt * 64 + trow) * NQKV +
                       CDIM + NKV * HSZ + g * HSZ + cb;
#pragma unroll
    for (int j = 0; j < 16; j += 4) {
        float4 v = *(const float4*)(src + j);
        tile[trow][cb + j + 0] = v.x;
        tile[trow][cb + j + 1] = v.y;
        tile[trow][cb + j + 2] = v.z;
        tile[trow][cb + j + 3] = v.w;
    }
    __syncthreads();
    const int d  = t >> 2;
    const int tb = (t & 3) * 16;
    short out[16] __attribute__((aligned(16)));
#pragma unroll
    for (int j = 0; j < 16; ++j) out[j] = f2bf(tile[tb + j][d]);
    short* dst = Vt + (((size_t)(b * NKV + g)) * HSZ + d) * TSEQ + tt * 64 + tb;
    *(bf16x8*)dst       = *(const bf16x8*)&out[0];
    *(bf16x8*)(dst + 8) = *(const bf16x8*)&out[8];
}

// ---------------------------------------------------------------------------
// Flash attention, bf16 MFMA (16x16x32). grid = (T/64, NH, B), block 256.
// Wave w owns q-rows [qt*64 + w*16, +16). KV tiles of 64 keys, double-buffered.
// ---------------------------------------------------------------------------
__global__ __launch_bounds__(256)
void attn_mfma(const short* __restrict__ Qh, const short* __restrict__ Kh,
               const short* __restrict__ Vt, float* __restrict__ y) {
    constexpr int LDR = 72;   // padded row (bf16 elems): 144B stride -> 2-way banks (free)
    __shared__ short Ks[2][64 * LDR];
    __shared__ short Vs[2][64 * LDR];
    __shared__ short Ps[4][16 * LDR];

    const int qt = blockIdx.x, h = blockIdx.y, b = blockIdx.z;
    const int g  = h >> 2;
    const int t  = threadIdx.x;
    const int wave = t >> 6, lane = t & 63;
    const int l16 = lane & 15, l4 = lane >> 4;

    // Q A-fragments: lane supplies A[row=l16][k = ks*32 + l4*8 + j]
    const short* qbase =
        Qh + (((size_t)(b * NHEADS + h)) * TSEQ + qt * 64 + wave * 16 + l16) * HSZ;
    const bf16x8 qfrag0 = *(const bf16x8*)(qbase + l4 * 8);
    const bf16x8 qfrag1 = *(const bf16x8*)(qbase + 32 + l4 * 8);

    const short* kgbase = Kh + ((size_t)(b * NKV + g)) * TSEQ * HSZ;  // [T][64]
    const short* vgbase = Vt + ((size_t)(b * NKV + g)) * HSZ * TSEQ;  // [64][T]

    // staging: 512 16B-chunks per tile, 2 per thread
    const int c0 = t,       r0 = c0 >> 3, o0 = (c0 & 7) * 8;
    const int c1 = t + 256, r1 = c1 >> 3, o1 = (c1 & 7) * 8;

    bf16x8 kreg0 = *(const bf16x8*)(kgbase + (size_t)r0 * HSZ + o0);
    bf16x8 kreg1 = *(const bf16x8*)(kgbase + (size_t)r1 * HSZ + o1);
    bf16x8 vreg0 = *(const bf16x8*)(vgbase + (size_t)r0 * TSEQ + o0);
    bf16x8 vreg1 = *(const bf16x8*)(vgbase + (size_t)r1 * TSEQ + o1);
    *(bf16x8*)&Ks[0][r0 * LDR + o0] = kreg0;
    *(bf16x8*)&Ks[0][r1 * LDR + o1] = kreg1;
    *(bf16x8*)&Vs[0][r0 * LDR + o0] = vreg0;
    *(bf16x8*)&Vs[0][r1 * LDR + o1] = vreg1;
    __syncthreads();

    f32x4 oacc[4];
#pragma unroll
    for (int df = 0; df < 4; ++df) oacc[df] = (f32x4){0.f, 0.f, 0.f, 0.f};
    float m_run[4] = {-1e30f, -1e30f, -1e30f, -1e30f};
    float l_run[4] = {0.f, 0.f, 0.f, 0.f};

    for (int kt = 0; kt <= qt; ++kt) {
        const int cur = kt & 1;

        if (kt < qt) {  // issue next tile's global loads (latency hides under MFMA)
            const size_t kb = (size_t)(kt + 1) * 64;
            kreg0 = *(const bf16x8*)(kgbase + (kb + r0) * HSZ + o0);
            kreg1 = *(const bf16x8*)(kgbase + (kb + r1) * HSZ + o1);
            vreg0 = *(const bf16x8*)(vgbase + (size_t)r0 * TSEQ + kb + o0);
            vreg1 = *(const bf16x8*)(vgbase + (size_t)r1 * TSEQ + kb + o1);
        }

        // ---- S = Q @ K^T (per wave: 16 x 64) ----
        f32x4 sacc[4];
#pragma unroll
        for (int kf = 0; kf < 4; ++kf) sacc[kf] = (f32x4){0.f, 0.f, 0.f, 0.f};
#pragma unroll
        for (int kf = 0; kf < 4; ++kf) {
            bf16x8 kb0 = *(const bf16x8*)&Ks[cur][(l16 + 16 * kf) * LDR + l4 * 8];
            sacc[kf] = __builtin_amdgcn_mfma_f32_16x16x32_bf16(qfrag0, kb0, sacc[kf], 0, 0, 0);
            bf16x8 kb1 = *(const bf16x8*)&Ks[cur][(l16 + 16 * kf) * LDR + 32 + l4 * 8];
            sacc[kf] = __builtin_amdgcn_mfma_f32_16x16x32_bf16(qfrag1, kb1, sacc[kf], 0, 0, 0);
        }

        // ---- online softmax; C layout: row=(lane>>4)*4+r, col=lane&15 ----
        const int qgb = qt * 64 + wave * 16 + l4 * 4;
        const int kgb = kt * 64 + l16;
#pragma unroll
        for (int r = 0; r < 4; ++r) {
            if (kt == qt) {
#pragma unroll
                for (int kf = 0; kf < 4; ++kf)
                    if (kgb + 16 * kf > qgb + r) sacc[kf][r] = -1e30f;
            }
            float mx = fmaxf(fmaxf(sacc[0][r], sacc[1][r]),
                             fmaxf(sacc[2][r], sacc[3][r]));
            mx = fmaxf(mx, __shfl_xor(mx, 1));
            mx = fmaxf(mx, __shfl_xor(mx, 2));
            mx = fmaxf(mx, __shfl_xor(mx, 4));
            mx = fmaxf(mx, __shfl_xor(mx, 8));
            const float mnew  = fmaxf(m_run[r], mx);
            const float alpha = __expf(m_run[r] - mnew);
            float psum = 0.f;
#pragma unroll
            for (int kf = 0; kf < 4; ++kf) {
                float p = __expf(sacc[kf][r] - mnew);
                psum += p;
                Ps[wave][(l4 * 4 + r) * LDR + l16 + 16 * kf] = f2bf(p);
            }
            psum += __shfl_xor(psum, 1);
            psum += __shfl_xor(psum, 2);
            psum += __shfl_xor(psum, 4);
            psum += __shfl_xor(psum, 8);
            l_run[r] = l_run[r] * alpha + psum;
            m_run[r] = mnew;
#pragma unroll
            for (int df = 0; df < 4; ++df) oacc[df][r] *= alpha;
        }

        // ---- O += P @ V  (P wave-private in LDS, no barrier needed) ----
#pragma unroll
        for (int ks = 0; ks < 2; ++ks) {
            bf16x8 pa = *(const bf16x8*)&Ps[wave][l16 * LDR + ks * 32 + l4 * 8];
#pragma unroll
            for (int df = 0; df < 4; ++df) {
                bf16x8 vb = *(const bf16x8*)&Vs[cur][(l16 + 16 * df) * LDR + ks * 32 + l4 * 8];
                oacc[df] = __builtin_amdgcn_mfma_f32_16x16x32_bf16(pa, vb, oacc[df], 0, 0, 0);
            }
        }

        if (kt < qt) {  // write staged regs into the other buffer
            *(bf16x8*)&Ks[cur ^ 1][r0 * LDR + o0] = kreg0;
            *(bf16x8*)&Ks[cur ^ 1][r1 * LDR + o1] = kreg1;
            *(bf16x8*)&Vs[cur ^ 1][r0 * LDR + o0] = vreg0;
            *(bf16x8*)&Vs[cur ^ 1][r1 * LDR + o1] = vreg1;
        }
        __syncthreads();
    }

    // ---- finalize: y[b*T + q][h*64 + d] ----
    const int orow = b * TSEQ + qt * 64 + wave * 16 + l4 * 4;
#pragma unroll
    for (int r = 0; r < 4; ++r) {
        const float inv = 1.0f / l_run[r];
#pragma unroll
        for (int df = 0; df < 4; ++df)
            y[(size_t)(orow + r) * CDIM + h * HSZ + 16 * df + l16] = oacc[df][r] * inv;
    }
}

// ---------------------------------------------------------------------------
extern "C" void kernel_launch(void* const* d_in, const int* in_sizes, int n_in,
                              void* d_out, int out_size, void* d_ws, size_t ws_size,
                              hipStream_t stream) {
    const float* x     = (const float*)d_in[0];
    const float* fcos  = (const float*)d_in[1];
    const float* fsin  = (const float*)d_in[2];
    const float* Wqkv  = (const float*)d_in[3];
    const float* bqkv  = (const float*)d_in[4];
    const float* Wproj = (const float*)d_in[5];
    const float* bproj = (const float*)d_in[6];
    float* out = (float*)d_out;

    char* ws = (char*)d_ws;
    float* qkv = (float*)ws;                                     // 50.3 MB
    ws += (size_t)MROWS * NQKV * sizeof(float);
    float* y = (float*)ws;                                       // 33.6 MB
    ws += (size_t)MROWS * CDIM * sizeof(float);
    short* Qh = (short*)ws;                                      // 16.8 MB
    ws += (size_t)BATCH * NHEADS * TSEQ * HSZ * sizeof(short);
    short* Kh = (short*)ws;                                      // 4.2 MB
    ws += (size_t)BATCH * NKV * TSEQ * HSZ * sizeof(short);
    short* Vt = (short*)ws;                                      // 4.2 MB

    // 1) QKV projection (fp32)
    gemm_bias_f32<<<dim3(NQKV / 128, MROWS / 128), 256, 0, stream>>>(
        x, Wqkv, bqkv, qkv, MROWS, NQKV, CDIM);

    // 2) RoPE + bf16 repack of Q,K ; V transpose to bf16
    {
        const int total = MROWS * (NHEADS + NKV) * (HSZ / 2);
        repack_qk<<<(total + 255) / 256, 256, 0, stream>>>(qkv, fcos, fsin, Qh, Kh);
    }
    transpose_v<<<dim3(TSEQ / 64, NKV, BATCH), 256, 0, stream>>>(qkv, Vt);

    // 3) bf16 MFMA flash attention -> y (fp32)
    attn_mfma<<<dim3(TSEQ / 64, NHEADS, BATCH), 256, 0, stream>>>(Qh, Kh, Vt, y);

    // 4) output projection (fp32)
    gemm_bias_f32<<<dim3(CDIM / 128, MROWS / 128), 256, 0, stream>>>(
        y, Wproj, bproj, out, MROWS, CDIM, CDIM);
}

// Round 3
// 474.001 us; speedup vs baseline: 7.0399x; 2.7784x over previous
//
#include <hip/hip_runtime.h>
#include <hip/hip_bf16.h>

#define TSEQ  2048
#define CDIM  2048
#define NHEADS 32
#define NKV    8
#define HSZ    64
#define BATCH  2
#define MROWS  (BATCH * TSEQ)            // 4096
#define NQKV   (CDIM + 2 * NKV * HSZ)    // 3072

typedef __attribute__((ext_vector_type(8))) short bf16x8;
typedef __attribute__((ext_vector_type(4))) float f32x4;

static __device__ __forceinline__ short f2bf(float f) {
    __hip_bfloat16 h = __float2bfloat16(f);
    short s;
    __builtin_memcpy(&s, &h, 2);
    return s;
}

// async global->LDS, 16B per lane.  LDS dest must be wave-uniform base;
// HW writes base + lane*16.
static __device__ __forceinline__ void gload_lds16(const void* g, void* l) {
    __builtin_amdgcn_global_load_lds(
        (const __attribute__((address_space(1))) unsigned int*)g,
        (__attribute__((address_space(3))) unsigned int*)l, 16, 0, 0);
}

// ---------------------------------------------------------------------------
// bf16 MFMA GEMM (m97 structure): C[M,N] = A[M,K] @ Bt[N,K]^T + bias.
// 128x128 tile, BK=32, 4 waves, 4x4 16x16x32 fragments/wave, double-buffered
// LDS fed by global_load_lds dwordx4.
// ---------------------------------------------------------------------------
__global__ __launch_bounds__(256)
void gemm_bf16(const short* __restrict__ A, const short* __restrict__ Bt,
               const float* __restrict__ bias, float* __restrict__ C,
               int M, int N, int K) {
    __shared__ short As[2][128 * 32];
    __shared__ short Bs[2][128 * 32];

    const int t    = threadIdx.x;
    const int wave = t >> 6, lane = t & 63;
    const int l16  = lane & 15, l4 = lane >> 4;
    const int wr   = wave >> 1, wc = wave & 1;
    const int m0   = blockIdx.y * 128, n0 = blockIdx.x * 128;

    const int srow = lane >> 2;        // row within a 16-row staging group
    const int scol = (lane & 3) * 8;   // bf16-element col offset (16B chunks)

    const short* Ab = A + (size_t)m0 * K;
    const short* Bb = Bt + (size_t)n0 * K;

    f32x4 acc[4][4];
#pragma unroll
    for (int mi = 0; mi < 4; ++mi)
#pragma unroll
        for (int ni = 0; ni < 4; ++ni) acc[mi][ni] = (f32x4){0.f, 0.f, 0.f, 0.f};

    const int nk = K / 32;

    // prologue: stage K-tile 0 into buffer 0
#pragma unroll
    for (int i = 0; i < 2; ++i) {
        const int rg = (i * 4 + wave) * 16;   // wave-uniform row-group base
        gload_lds16(Ab + (size_t)(rg + srow) * K + scol, &As[0][rg * 32]);
        gload_lds16(Bb + (size_t)(rg + srow) * K + scol, &Bs[0][rg * 32]);
    }
    __syncthreads();   // implies vmcnt(0) drain

    for (int kt = 0; kt < nk; ++kt) {
        const int cur = kt & 1;
        if (kt + 1 < nk) {   // issue next tile's DMA before compute
            const int k0 = (kt + 1) * 32;
#pragma unroll
            for (int i = 0; i < 2; ++i) {
                const int rg = (i * 4 + wave) * 16;
                gload_lds16(Ab + (size_t)(rg + srow) * K + k0 + scol,
                            &As[cur ^ 1][rg * 32]);
                gload_lds16(Bb + (size_t)(rg + srow) * K + k0 + scol,
                            &Bs[cur ^ 1][rg * 32]);
            }
        }

        bf16x8 af[4], bfr[4];
#pragma unroll
        for (int mi = 0; mi < 4; ++mi)
            af[mi] = *(const bf16x8*)&As[cur][(wr * 64 + mi * 16 + l16) * 32 + l4 * 8];
#pragma unroll
        for (int ni = 0; ni < 4; ++ni)
            bfr[ni] = *(const bf16x8*)&Bs[cur][(wc * 64 + ni * 16 + l16) * 32 + l4 * 8];
#pragma unroll
        for (int mi = 0; mi < 4; ++mi)
#pragma unroll
            for (int ni = 0; ni < 4; ++ni)
                acc[mi][ni] = __builtin_amdgcn_mfma_f32_16x16x32_bf16(
                    af[mi], bfr[ni], acc[mi][ni], 0, 0, 0);

        __syncthreads();   // drains next tile's DMA + this tile's ds_reads
    }

    // epilogue: C = acc + bias   (C/D layout: col=lane&15, row=(lane>>4)*4+r)
#pragma unroll
    for (int ni = 0; ni < 4; ++ni) {
        const int col = n0 + wc * 64 + ni * 16 + l16;
        const float bv = bias[col];
#pragma unroll
        for (int mi = 0; mi < 4; ++mi) {
            const int row = m0 + wr * 64 + mi * 16 + l4 * 4;
#pragma unroll
            for (int r = 0; r < 4; ++r)
                C[(size_t)(row + r) * N + col] = acc[mi][ni][r] + bv;
        }
    }
}

// ---------------------------------------------------------------------------
// x (fp32) -> bf16, same layout
// ---------------------------------------------------------------------------
__global__ void cast_f32_bf16(const float* __restrict__ src,
                              short* __restrict__ dst, int n8) {
    int i = blockIdx.x * blockDim.x + threadIdx.x;
    if (i >= n8) return;
    float4 v0 = ((const float4*)src)[2 * i];
    float4 v1 = ((const float4*)src)[2 * i + 1];
    short o[8] __attribute__((aligned(16)));
    o[0] = f2bf(v0.x); o[1] = f2bf(v0.y); o[2] = f2bf(v0.z); o[3] = f2bf(v0.w);
    o[4] = f2bf(v1.x); o[5] = f2bf(v1.y); o[6] = f2bf(v1.z); o[7] = f2bf(v1.w);
    *(bf16x8*)(dst + 8 * i) = *(const bf16x8*)o;
}

// ---------------------------------------------------------------------------
// W [K][N] fp32 -> Wt [N][K] bf16   (64x64 LDS tiles)
// ---------------------------------------------------------------------------
__global__ __launch_bounds__(256)
void transpose_cast(const float* __restrict__ W, short* __restrict__ Wt,
                    int K, int N) {
    __shared__ float tile[64][65];
    const int n0 = blockIdx.x * 64, k0 = blockIdx.y * 64;
    const int t = threadIdx.x;
    const int r = t >> 2, cb = (t & 3) * 16;
    const float* src = W + (size_t)(k0 + r) * N + n0 + cb;
#pragma unroll
    for (int j = 0; j < 16; j += 4) {
        float4 v = *(const float4*)(src + j);
        tile[r][cb + j + 0] = v.x;
        tile[r][cb + j + 1] = v.y;
        tile[r][cb + j + 2] = v.z;
        tile[r][cb + j + 3] = v.w;
    }
    __syncthreads();
    short o[16] __attribute__((aligned(16)));
#pragma unroll
    for (int j = 0; j < 16; ++j) o[j] = f2bf(tile[cb + j][r]);
    short* dst = Wt + (size_t)(n0 + r) * K + k0 + cb;
    *(bf16x8*)dst       = *(const bf16x8*)&o[0];
    *(bf16x8*)(dst + 8) = *(const bf16x8*)&o[8];
}

// ---------------------------------------------------------------------------
// RoPE + cast to bf16:  Qh[b][h][T][64] (pre-scaled 1/8), Kh[b][g][T][64]
// ---------------------------------------------------------------------------
__global__ void repack_qk(const float* __restrict__ qkv,
                          const float* __restrict__ cs,
                          const float* __restrict__ sn,
                          short* __restrict__ Qh, short* __restrict__ Kh) {
    const int total = MROWS * (NHEADS + NKV) * (HSZ / 2);
    int idx = blockIdx.x * blockDim.x + threadIdx.x;
    if (idx >= total) return;
    const int i    = idx & 31;
    int tmp        = idx >> 5;
    const int head = tmp % (NHEADS + NKV);
    const int row  = tmp / (NHEADS + NKV);
    const int tpos = row & (TSEQ - 1);
    const int b    = row >> 11;
    const float c  = cs[tpos * (HSZ / 2) + i];
    const float s  = sn[tpos * (HSZ / 2) + i];
    const int col  = (head < NHEADS) ? head * HSZ + 2 * i
                                     : CDIM + (head - NHEADS) * HSZ + 2 * i;
    float2 v = *(const float2*)(qkv + (size_t)row * NQKV + col);
    const float re = v.x * c - v.y * s;
    const float im = v.x * s + v.y * c;
    if (head < NHEADS) {
        size_t o = (((size_t)(b * NHEADS + head)) * TSEQ + tpos) * HSZ + 2 * i;
        Qh[o]     = f2bf(re * 0.125f);
        Qh[o + 1] = f2bf(im * 0.125f);
    } else {
        const int kh = head - NHEADS;
        size_t o = (((size_t)(b * NKV + kh)) * TSEQ + tpos) * HSZ + 2 * i;
        Kh[o]     = f2bf(re);
        Kh[o + 1] = f2bf(im);
    }
}

// ---------------------------------------------------------------------------
// V -> bf16, transposed: Vt[b][g][d=64][T]
// ---------------------------------------------------------------------------
__global__ __launch_bounds__(256)
void transpose_v(const float* __restrict__ qkv, short* __restrict__ Vt) {
    __shared__ float tile[64][65];
    const int tt = blockIdx.x, g = blockIdx.y, b = blockIdx.z;
    const int t  = threadIdx.x;
    const int trow = t >> 2;
    const int cb   = (t & 3) * 16;
    const float* src = qkv + (size_t)(b * TSEQ + tt * 64 + trow) * NQKV +
                       CDIM + NKV * HSZ + g * HSZ + cb;
#pragma unroll
    for (int j = 0; j < 16; j += 4) {
        float4 v = *(const float4*)(src + j);
        tile[trow][cb + j + 0] = v.x;
        tile[trow][cb + j + 1] = v.y;
        tile[trow][cb + j + 2] = v.z;
        tile[trow][cb + j + 3] = v.w;
    }
    __syncthreads();
    const int d  = t >> 2;
    const int tb = (t & 3) * 16;
    short out[16] __attribute__((aligned(16)));
#pragma unroll
    for (int j = 0; j < 16; ++j) out[j] = f2bf(tile[tb + j][d]);
    short* dst = Vt + (((size_t)(b * NKV + g)) * HSZ + d) * TSEQ + tt * 64 + tb;
    *(bf16x8*)dst       = *(const bf16x8*)&out[0];
    *(bf16x8*)(dst + 8) = *(const bf16x8*)&out[8];
}

// ---------------------------------------------------------------------------
// Flash attention, bf16 MFMA (16x16x32). grid = (T/64, NH, B), block 256.
// Output written as bf16 (feeds the proj GEMM).
// ---------------------------------------------------------------------------
__global__ __launch_bounds__(256)
void attn_mfma(const short* __restrict__ Qh, const short* __restrict__ Kh,
               const short* __restrict__ Vt, short* __restrict__ Yb) {
    constexpr int LDR = 72;
    __shared__ short Ks[2][64 * LDR];
    __shared__ short Vs[2][64 * LDR];
    __shared__ short Ps[4][16 * LDR];

    const int qt = blockIdx.x, h = blockIdx.y, b = blockIdx.z;
    const int g  = h >> 2;
    const int t  = threadIdx.x;
    const int wave = t >> 6, lane = t & 63;
    const int l16 = lane & 15, l4 = lane >> 4;

    const short* qbase =
        Qh + (((size_t)(b * NHEADS + h)) * TSEQ + qt * 64 + wave * 16 + l16) * HSZ;
    const bf16x8 qfrag0 = *(const bf16x8*)(qbase + l4 * 8);
    const bf16x8 qfrag1 = *(const bf16x8*)(qbase + 32 + l4 * 8);

    const short* kgbase = Kh + ((size_t)(b * NKV + g)) * TSEQ * HSZ;  // [T][64]
    const short* vgbase = Vt + ((size_t)(b * NKV + g)) * HSZ * TSEQ;  // [64][T]

    const int c0 = t,       r0 = c0 >> 3, o0 = (c0 & 7) * 8;
    const int c1 = t + 256, r1 = c1 >> 3, o1 = (c1 & 7) * 8;

    bf16x8 kreg0 = *(const bf16x8*)(kgbase + (size_t)r0 * HSZ + o0);
    bf16x8 kreg1 = *(const bf16x8*)(kgbase + (size_t)r1 * HSZ + o1);
    bf16x8 vreg0 = *(const bf16x8*)(vgbase + (size_t)r0 * TSEQ + o0);
    bf16x8 vreg1 = *(const bf16x8*)(vgbase + (size_t)r1 * TSEQ + o1);
    *(bf16x8*)&Ks[0][r0 * LDR + o0] = kreg0;
    *(bf16x8*)&Ks[0][r1 * LDR + o1] = kreg1;
    *(bf16x8*)&Vs[0][r0 * LDR + o0] = vreg0;
    *(bf16x8*)&Vs[0][r1 * LDR + o1] = vreg1;
    __syncthreads();

    f32x4 oacc[4];
#pragma unroll
    for (int df = 0; df < 4; ++df) oacc[df] = (f32x4){0.f, 0.f, 0.f, 0.f};
    float m_run[4] = {-1e30f, -1e30f, -1e30f, -1e30f};
    float l_run[4] = {0.f, 0.f, 0.f, 0.f};

    for (int kt = 0; kt <= qt; ++kt) {
        const int cur = kt & 1;

        if (kt < qt) {
            const size_t kb = (size_t)(kt + 1) * 64;
            kreg0 = *(const bf16x8*)(kgbase + (kb + r0) * HSZ + o0);
            kreg1 = *(const bf16x8*)(kgbase + (kb + r1) * HSZ + o1);
            vreg0 = *(const bf16x8*)(vgbase + (size_t)r0 * TSEQ + kb + o0);
            vreg1 = *(const bf16x8*)(vgbase + (size_t)r1 * TSEQ + kb + o1);
        }

        f32x4 sacc[4];
#pragma unroll
        for (int kf = 0; kf < 4; ++kf) sacc[kf] = (f32x4){0.f, 0.f, 0.f, 0.f};
#pragma unroll
        for (int kf = 0; kf < 4; ++kf) {
            bf16x8 kb0 = *(const bf16x8*)&Ks[cur][(l16 + 16 * kf) * LDR + l4 * 8];
            sacc[kf] = __builtin_amdgcn_mfma_f32_16x16x32_bf16(qfrag0, kb0, sacc[kf], 0, 0, 0);
            bf16x8 kb1 = *(const bf16x8*)&Ks[cur][(l16 + 16 * kf) * LDR + 32 + l4 * 8];
            sacc[kf] = __builtin_amdgcn_mfma_f32_16x16x32_bf16(qfrag1, kb1, sacc[kf], 0, 0, 0);
        }

        const int qgb = qt * 64 + wave * 16 + l4 * 4;
        const int kgb = kt * 64 + l16;
#pragma unroll
        for (int r = 0; r < 4; ++r) {
            if (kt == qt) {
#pragma unroll
                for (int kf = 0; kf < 4; ++kf)
                    if (kgb + 16 * kf > qgb + r) sacc[kf][r] = -1e30f;
            }
            float mx = fmaxf(fmaxf(sacc[0][r], sacc[1][r]),
                             fmaxf(sacc[2][r], sacc[3][r]));
            mx = fmaxf(mx, __shfl_xor(mx, 1));
            mx = fmaxf(mx, __shfl_xor(mx, 2));
            mx = fmaxf(mx, __shfl_xor(mx, 4));
            mx = fmaxf(mx, __shfl_xor(mx, 8));
            const float mnew  = fmaxf(m_run[r], mx);
            const float alpha = __expf(m_run[r] - mnew);
            float psum = 0.f;
#pragma unroll
            for (int kf = 0; kf < 4; ++kf) {
                float p = __expf(sacc[kf][r] - mnew);
                psum += p;
                Ps[wave][(l4 * 4 + r) * LDR + l16 + 16 * kf] = f2bf(p);
            }
            psum += __shfl_xor(psum, 1);
            psum += __shfl_xor(psum, 2);
            psum += __shfl_xor(psum, 4);
            psum += __shfl_xor(psum, 8);
            l_run[r] = l_run[r] * alpha + psum;
            m_run[r] = mnew;
#pragma unroll
            for (int df = 0; df < 4; ++df) oacc[df][r] *= alpha;
        }

#pragma unroll
        for (int ks = 0; ks < 2; ++ks) {
            bf16x8 pa = *(const bf16x8*)&Ps[wave][l16 * LDR + ks * 32 + l4 * 8];
#pragma unroll
            for (int df = 0; df < 4; ++df) {
                bf16x8 vb = *(const bf16x8*)&Vs[cur][(l16 + 16 * df) * LDR + ks * 32 + l4 * 8];
                oacc[df] = __builtin_amdgcn_mfma_f32_16x16x32_bf16(pa, vb, oacc[df], 0, 0, 0);
            }
        }

        if (kt < qt) {
            *(bf16x8*)&Ks[cur ^ 1][r0 * LDR + o0] = kreg0;
            *(bf16x8*)&Ks[cur ^ 1][r1 * LDR + o1] = kreg1;
            *(bf16x8*)&Vs[cur ^ 1][r0 * LDR + o0] = vreg0;
            *(bf16x8*)&Vs[cur ^ 1][r1 * LDR + o1] = vreg1;
        }
        __syncthreads();
    }

    const int orow = b * TSEQ + qt * 64 + wave * 16 + l4 * 4;
#pragma unroll
    for (int r = 0; r < 4; ++r) {
        const float inv = 1.0f / l_run[r];
#pragma unroll
        for (int df = 0; df < 4; ++df)
            Yb[(size_t)(orow + r) * CDIM + h * HSZ + 16 * df + l16] =
                f2bf(oacc[df][r] * inv);
    }
}

// ---------------------------------------------------------------------------
extern "C" void kernel_launch(void* const* d_in, const int* in_sizes, int n_in,
                              void* d_out, int out_size, void* d_ws, size_t ws_size,
                              hipStream_t stream) {
    const float* x     = (const float*)d_in[0];
    const float* fcos  = (const float*)d_in[1];
    const float* fsin  = (const float*)d_in[2];
    const float* Wqkv  = (const float*)d_in[3];
    const float* bqkv  = (const float*)d_in[4];
    const float* Wproj = (const float*)d_in[5];
    const float* bproj = (const float*)d_in[6];
    float* out = (float*)d_out;

    char* ws = (char*)d_ws;
    float* qkv = (float*)ws;   ws += (size_t)MROWS * NQKV * sizeof(float);   // 50.3 MB
    short* Qh  = (short*)ws;   ws += (size_t)BATCH * NHEADS * TSEQ * HSZ * 2; // 16.8 MB
    short* Kh  = (short*)ws;   ws += (size_t)BATCH * NKV * TSEQ * HSZ * 2;    //  4.2 MB
    short* Vt  = (short*)ws;   ws += (size_t)BATCH * NKV * TSEQ * HSZ * 2;    //  4.2 MB
    short* Yb  = (short*)ws;   ws += (size_t)MROWS * CDIM * 2;                // 16.8 MB
    short* Xb  = (short*)ws;   ws += (size_t)MROWS * CDIM * 2;                // 16.8 MB
    short* Wqkv_t = (short*)ws; ws += (size_t)NQKV * CDIM * 2;                // 12.6 MB
    short* Wproj_t = (short*)ws;                                              //  8.4 MB

    // input casts / weight transposes (one pass each, memory-bound)
    cast_f32_bf16<<<(MROWS * CDIM / 8 + 255) / 256, 256, 0, stream>>>(
        x, Xb, MROWS * CDIM / 8);
    transpose_cast<<<dim3(NQKV / 64, CDIM / 64), 256, 0, stream>>>(
        Wqkv, Wqkv_t, CDIM, NQKV);
    transpose_cast<<<dim3(CDIM / 64, CDIM / 64), 256, 0, stream>>>(
        Wproj, Wproj_t, CDIM, CDIM);

    // 1) QKV projection (bf16 MFMA, fp32 out)
    gemm_bf16<<<dim3(NQKV / 128, MROWS / 128), 256, 0, stream>>>(
        Xb, Wqkv_t, bqkv, qkv, MROWS, NQKV, CDIM);

    // 2) RoPE + repack, V transpose
    {
        const int total = MROWS * (NHEADS + NKV) * (HSZ / 2);
        repack_qk<<<(total + 255) / 256, 256, 0, stream>>>(qkv, fcos, fsin, Qh, Kh);
    }
    transpose_v<<<dim3(TSEQ / 64, NKV, BATCH), 256, 0, stream>>>(qkv, Vt);

    // 3) attention -> Yb (bf16)
    attn_mfma<<<dim3(TSEQ / 64, NHEADS, BATCH), 256, 0, stream>>>(Qh, Kh, Vt, Yb);

    // 4) output projection (bf16 MFMA, fp32 out + bias)
    gemm_bf16<<<dim3(CDIM / 128, MROWS / 128), 256, 0, stream>>>(
        Yb, Wproj_t, bproj, out, MROWS, CDIM, CDIM);
}